// Round 2
// baseline (7139.295 us; speedup 1.0000x reference)
//
#include <hip/hip_runtime.h>
#include <hip/hip_bf16.h>

#define TT 3650
#define HH 256

typedef _Float16 f16x2 __attribute__((ext_vector_type(2)));
typedef _Float16 f16x8 __attribute__((ext_vector_type(8)));
struct H4q { f16x2 a, b, c, d; };

__device__ __forceinline__ float xexp2(float x) { return __builtin_amdgcn_exp2f(x); }
__device__ __forceinline__ float xrcp(float x) { return __builtin_amdgcn_rcpf(x); }
__device__ __forceinline__ float xexp(float x) { return xexp2(x * 1.4426950408889634f); }
__device__ __forceinline__ float xtanh(float x) {
  float e = xexp2(x * 2.8853900817779268f);  // e^{2x}
  return 1.0f - 2.0f * xrcp(e + 1.0f);
}
// _step_function(x) = (tanh(5x)+1)/2 == sigmoid(10x)
__device__ __forceinline__ float xstep(float x) {
  return xrcp(1.0f + xexp2(-14.426950408889634f * x));
}
__device__ __forceinline__ float xsinh(float x) {
  float e = xexp(x);
  return 0.5f * (e - xrcp(e));
}

#if __has_builtin(__builtin_amdgcn_fdot2)
__device__ __forceinline__ float xdot2(f16x2 a, f16x2 b, float c) {
  return __builtin_amdgcn_fdot2(a, b, c, false);
}
#else
__device__ __forceinline__ float xdot2(f16x2 a, f16x2 b, float c) {
  return c + (float)a[0] * (float)b[0] + (float)a[1] * (float)b[1];
}
#endif

__global__ __launch_bounds__(512, 2) void exphydro_scan(
    const float* __restrict__ gin, const float* __restrict__ gdayl,
    const float* __restrict__ gW0, const float* __restrict__ gb0,
    const float* __restrict__ gW1, const float* __restrict__ gb1,
    const float* __restrict__ gW2, const float* __restrict__ gb2,
    const float* __restrict__ gWout, const float* __restrict__ gbout,
    float* __restrict__ gout) {
  __shared__ float sW0[4 * HH];              // 4 KB
  __shared__ float sB0[HH], sB1[HH], sB2[HH];
  __shared__ float sWout[5 * HH];            // 5 KB
  __shared__ float sBout[5];
  __shared__ float sWP[64];                  // per-wave output partials [wave][m]
  __shared__ float sState[2];
  __shared__ alignas(16) _Float16 h0h[HH];   // packed fp16 activations
  __shared__ alignas(16) _Float16 h1h[HH];
  __shared__ float sP[TT], sTm[TT], sLd[TT]; // staged forcings (43.8 KB)

  const int tid = threadIdx.x;
  const int j = tid >> 1;      // output neuron 0..255
  const int q = tid & 1;       // k-half 0..1 (k in [128q, 128q+128))
  const int lane = tid & 63;
  const int wave = tid >> 6;

  // ---- stage small weights + forcings to LDS ----
  for (int i = tid; i < 4 * HH; i += 512) sW0[i] = gW0[i];
  if (tid < HH) { sB0[tid] = gb0[tid]; sB1[tid] = gb1[tid]; sB2[tid] = gb2[tid]; }
  for (int i = tid; i < 5 * HH; i += 512) sWout[i] = gWout[i];
  if (tid < 5) sBout[tid] = gbout[tid];
  if (tid == 0) { sState[0] = gin[0]; sState[1] = gin[1]; }  // inputs[0,0], inputs[0,1]
  for (int i = tid; i < TT; i += 512) {
    sP[i] = gin[5 * i + 2];
    sTm[i] = gin[5 * i + 3];
    sLd[i] = gdayl[i];
  }

  // ---- one-time: load big weights into registers as packed fp16 ----
  // thread (j,q) holds W1[k][j], W2[k][j] for k in [128q,128q+128) as 64+64 f16x2
  f16x2 w1r[64], w2r[64];
  const int kbase = q * 128;
#pragma unroll
  for (int i = 0; i < 64; ++i) {
    int k = kbase + 2 * i;
    float a0 = gW1[k * HH + j];
    float a1 = gW1[(k + 1) * HH + j];
    float c0 = gW2[k * HH + j];
    float c1 = gW2[(k + 1) * HH + j];
    w1r[i] = f16x2{(_Float16)a0, (_Float16)a1};
    w2r[i] = f16x2{(_Float16)c0, (_Float16)c1};
  }

  const char* hb0 = (const char*)h0h + q * 256;  // this thread's 128-half window
  const char* hb1 = (const char*)h1h + q * 256;

  for (int t = 0; t < TT; ++t) {
    // forcings are immutable in LDS: read before the barrier, latency overlaps it
    const float p_in = sP[t];
    const float tm = sTm[t];
    const float ld = sLd[t];
    __syncthreads();  // publishes sState (and at t=0, all staging)
    const float s0 = sState[0];
    const float s1 = sState[1];
    if (tid == 0) {  // s_snow_nn[t], s_water_nn[t] are the PRE-update states
      gout[TT + t] = s0;
      gout[2 * TT + t] = s1;
    }

    // ---- layer 0: z0[j] = x . W0[:,j] + b0[j] (all threads, 2x redundant) ----
    float z0 = sB0[j] + s0 * sW0[j] + s1 * sW0[HH + j] + p_in * sW0[2 * HH + j] +
               tm * sW0[3 * HH + j];
    float h0v = xtanh(z0);
    if (q == 0) h0h[j] = (_Float16)h0v;
    __syncthreads();

    // ---- layer 1: 64 fdot2 over this thread's k-half ----
    float a0 = 0.f, a1 = 0.f, a2 = 0.f, a3 = 0.f;
#pragma unroll
    for (int s = 0; s < 16; ++s) {
      f16x8 hv = *(const f16x8*)(hb0 + s * 16);
      H4q hp = __builtin_bit_cast(H4q, hv);
      a0 = xdot2(hp.a, w1r[4 * s + 0], a0);
      a1 = xdot2(hp.b, w1r[4 * s + 1], a1);
      a2 = xdot2(hp.c, w1r[4 * s + 2], a2);
      a3 = xdot2(hp.d, w1r[4 * s + 3], a3);
    }
    float z1 = (a0 + a1) + (a2 + a3);
    z1 += __shfl_xor(z1, 1);  // combine the two k-halves
    float h1v = xtanh(z1 + sB1[j]);
    if (q == 0) h1h[j] = (_Float16)h1v;
    __syncthreads();

    // ---- layer 2 ----
    a0 = 0.f; a1 = 0.f; a2 = 0.f; a3 = 0.f;
#pragma unroll
    for (int s = 0; s < 16; ++s) {
      f16x8 hv = *(const f16x8*)(hb1 + s * 16);
      H4q hp = __builtin_bit_cast(H4q, hv);
      a0 = xdot2(hp.a, w2r[4 * s + 0], a0);
      a1 = xdot2(hp.b, w2r[4 * s + 1], a1);
      a2 = xdot2(hp.c, w2r[4 * s + 2], a2);
      a3 = xdot2(hp.d, w2r[4 * s + 3], a3);
    }
    float z2 = (a0 + a1) + (a2 + a3);
    z2 += __shfl_xor(z2, 1);
    float h2v = xtanh(z2 + sB2[j]);

    // ---- output layer: o[m] = sum_j h2[j]*Wout[j][m] + bout[m], m=0..4 ----
    float pa = h2v * sWout[5 * j + q];        // m = q
    float pb = h2v * sWout[5 * j + 2 + q];    // m = 2+q
    float pc = (q == 0) ? h2v * sWout[5 * j + 4] : 0.0f;  // m = 4
#pragma unroll
    for (int off = 2; off < 64; off <<= 1) {  // reduce over 32 j's, q preserved
      pa += __shfl_xor(pa, off);
      pb += __shfl_xor(pb, off);
      pc += __shfl_xor(pc, off);
    }
    if (lane == 0) {
      sWP[wave * 8 + 0] = pa; sWP[wave * 8 + 2] = pb; sWP[wave * 8 + 4] = pc;
    } else if (lane == 1) {
      sWP[wave * 8 + 1] = pa; sWP[wave * 8 + 3] = pb;
    }
    __syncthreads();

    // ---- finalize on wave 0: o[m], transforms, state update ----
    if (wave == 0) {
      float o = 0.0f;
      if (lane < 5) {
        o = sBout[lane];
#pragma unroll
        for (int w = 0; w < 8; ++w) o += sWP[w * 8 + lane];
      }
      if (lane == 4) gout[t] = o;  // q_output[t] = raw mlp output m=4
      // lane m computes transformed value m (lanes 5..63 compute garbage, unused)
      float sh = xsinh(o);
      float ex = xexp(o);
      float v0 = fmaxf(sh * xstep(-tm), 0.0f);          // p_snow
      float v1 = fmaxf(sh, 0.0f);                       // p_rain
      float v2 = fmaxf(xstep(s0) * sh, 0.0f);           // m
      float v3 = xstep(s1) * ex * ld;                   // et
      float v4 = xstep(s1) * ex;                        // q
      float val = lane == 0 ? v0 : lane == 1 ? v1 : lane == 2 ? v2 : lane == 3 ? v3 : v4;
      float psn = __shfl(val, 0);
      float prn = __shfl(val, 1);
      float mm  = __shfl(val, 2);
      float evt = __shfl(val, 3);
      float qq  = __shfl(val, 4);
      if (lane == 0) {
        sState[0] = s0 + (psn - mm);              // DT = 1
        sState[1] = s1 + (prn + mm - evt - qq);
      }
    }
  }
}

extern "C" void kernel_launch(void* const* d_in, const int* in_sizes, int n_in,
                              void* d_out, int out_size, void* d_ws, size_t ws_size,
                              hipStream_t stream) {
  const float* gin   = (const float*)d_in[0];
  const float* gdayl = (const float*)d_in[1];
  const float* gW0   = (const float*)d_in[2];
  const float* gb0   = (const float*)d_in[3];
  const float* gW1   = (const float*)d_in[4];
  const float* gb1   = (const float*)d_in[5];
  const float* gW2   = (const float*)d_in[6];
  const float* gb2   = (const float*)d_in[7];
  const float* gWout = (const float*)d_in[8];
  const float* gbout = (const float*)d_in[9];
  float* gout = (float*)d_out;
  exphydro_scan<<<dim3(1), dim3(512), 0, stream>>>(
      gin, gdayl, gW0, gb0, gW1, gb1, gW2, gb2, gWout, gbout, gout);
}

// Round 3
// 6705.207 us; speedup vs baseline: 1.0647x; 1.0647x over previous
//
#include <hip/hip_runtime.h>
#include <hip/hip_bf16.h>

#define TT 3650
#define HH 256

typedef _Float16 f16x2 __attribute__((ext_vector_type(2)));
typedef _Float16 f16x8 __attribute__((ext_vector_type(8)));
struct H4q { f16x2 a, b, c, d; };

__device__ __forceinline__ float xexp2(float x) { return __builtin_amdgcn_exp2f(x); }
__device__ __forceinline__ float xrcp(float x) { return __builtin_amdgcn_rcpf(x); }
__device__ __forceinline__ float xexp(float x) { return xexp2(x * 1.4426950408889634f); }
__device__ __forceinline__ float xtanh(float x) {
  float e = xexp2(x * 2.8853900817779268f);  // e^{2x}
  return 1.0f - 2.0f * xrcp(e + 1.0f);
}
// _step_function(x) = (tanh(5x)+1)/2 == sigmoid(10x)
__device__ __forceinline__ float xstep(float x) {
  return xrcp(1.0f + xexp2(-14.426950408889634f * x));
}
__device__ __forceinline__ float xsinh(float x) {
  float e = xexp(x);
  return 0.5f * (e - xrcp(e));
}

#if __has_builtin(__builtin_amdgcn_fdot2)
__device__ __forceinline__ float xdot2(f16x2 a, f16x2 b, float c) {
  return __builtin_amdgcn_fdot2(a, b, c, false);
}
#else
__device__ __forceinline__ float xdot2(f16x2 a, f16x2 b, float c) {
  return c + (float)a[0] * (float)b[0] + (float)a[1] * (float)b[1];
}
#endif

__global__ __launch_bounds__(512) void exphydro_scan(
    const float* __restrict__ gin, const float* __restrict__ gdayl,
    const float* __restrict__ gW0, const float* __restrict__ gb0,
    const float* __restrict__ gW1, const float* __restrict__ gb1,
    const float* __restrict__ gW2, const float* __restrict__ gb2,
    const float* __restrict__ gWout, const float* __restrict__ gbout,
    float* __restrict__ gout) {
  // activations: halves separated by 16B pad so the two per-wave broadcast
  // addresses of each ds_read_b128 land on disjoint bank groups
  __shared__ alignas(16) _Float16 h0h[HH + 8];
  __shared__ alignas(16) _Float16 h1h[HH + 8];
  __shared__ float sWP[64];                  // [m][wave] partials, m*8+w, 40 used
  __shared__ float sP[TT], sTm[TT], sLd[TT]; // staged forcings (43.8 KB)

  const int tid = threadIdx.x;
  const int j = tid >> 1;      // output neuron 0..255
  const int q = tid & 1;       // k-half 0..1 (k in [128q, 128q+128))
  const int lane = tid & 63;
  const int wave = tid >> 6;

  // ---- stage forcings to LDS ----
  for (int i = tid; i < TT; i += 512) {
    sP[i] = gin[5 * i + 2];
    sTm[i] = gin[5 * i + 3];
    sLd[i] = gdayl[i];
  }

  // ---- per-thread constants in registers (uniform ones become s_loads) ----
  float s0 = gin[0], s1 = gin[1];
  const float bo0 = gbout[0], bo1 = gbout[1], bo2 = gbout[2], bo3 = gbout[3],
              bo4 = gbout[4];
  const float w00 = gW0[j], w01 = gW0[HH + j], w02 = gW0[2 * HH + j],
              w03 = gW0[3 * HH + j];
  const float b0 = gb0[j], b1 = gb1[j], b2 = gb2[j];
  const float wo_a = gWout[5 * j + q];       // m = q
  const float wo_b = gWout[5 * j + 2 + q];   // m = 2+q
  const float wo_c = gWout[5 * j + 4];       // m = 4 (used by q==0)

  // ---- one-time: big weights into registers as packed fp16 ----
  // thread (j,q) holds W1[k][j], W2[k][j] for k in [128q,128q+128) as 64+64 f16x2
  f16x2 w1r[64], w2r[64];
  const int kbase = q * 128;
#pragma unroll
  for (int i = 0; i < 64; ++i) {
    int k = kbase + 2 * i;
    w1r[i] = f16x2{(_Float16)gW1[k * HH + j], (_Float16)gW1[(k + 1) * HH + j]};
    w2r[i] = f16x2{(_Float16)gW2[k * HH + j], (_Float16)gW2[(k + 1) * HH + j]};
  }

  const char* hb0 = (const char*)h0h + q * 272;  // this thread's 128-half window
  const char* hb1 = (const char*)h1h + q * 272;
  const int jw = j + ((j & 128) >> 4);           // +8 elements for upper half

  __syncthreads();  // staging visible

  for (int t = 0; t < TT; ++t) {
    const float p_in = sP[t];
    const float tm = sTm[t];
    const float ld = sLd[t];

    // ---- layer 0 (2x redundant across q) ----
    float z0 = b0 + s0 * w00 + s1 * w01 + p_in * w02 + tm * w03;
    float h0v = xtanh(z0);
    if (q == 0) h0h[jw] = (_Float16)h0v;
    __syncthreads();  // A

    // ---- layer 1: 64 fdot2 over this thread's k-half ----
    float a0 = 0.f, a1 = 0.f, a2 = 0.f, a3 = 0.f;
#pragma unroll
    for (int s = 0; s < 16; ++s) {
      f16x8 hv = *(const f16x8*)(hb0 + s * 16);
      H4q hp = __builtin_bit_cast(H4q, hv);
      a0 = xdot2(hp.a, w1r[4 * s + 0], a0);
      a1 = xdot2(hp.b, w1r[4 * s + 1], a1);
      a2 = xdot2(hp.c, w1r[4 * s + 2], a2);
      a3 = xdot2(hp.d, w1r[4 * s + 3], a3);
    }
    float z1 = (a0 + a1) + (a2 + a3);
    z1 += __shfl_xor(z1, 1);  // combine the two k-halves
    float h1v = xtanh(z1 + b1);
    if (q == 0) h1h[jw] = (_Float16)h1v;
    __syncthreads();  // B

    // ---- layer 2 ----
    a0 = 0.f; a1 = 0.f; a2 = 0.f; a3 = 0.f;
#pragma unroll
    for (int s = 0; s < 16; ++s) {
      f16x8 hv = *(const f16x8*)(hb1 + s * 16);
      H4q hp = __builtin_bit_cast(H4q, hv);
      a0 = xdot2(hp.a, w2r[4 * s + 0], a0);
      a1 = xdot2(hp.b, w2r[4 * s + 1], a1);
      a2 = xdot2(hp.c, w2r[4 * s + 2], a2);
      a3 = xdot2(hp.d, w2r[4 * s + 3], a3);
    }
    float z2 = (a0 + a1) + (a2 + a3);
    z2 += __shfl_xor(z2, 1);
    float h2v = xtanh(z2 + b2);

    // ---- output partials: in-wave reduce over j (q-parity carries m pairs) ----
    float pa = h2v * wo_a;                    // m = q
    float pb = h2v * wo_b;                    // m = 2+q
    float pc = (q == 0) ? h2v * wo_c : 0.0f;  // m = 4
#pragma unroll
    for (int off = 2; off < 64; off <<= 1) {
      pa += __shfl_xor(pa, off);
      pb += __shfl_xor(pb, off);
      pc += __shfl_xor(pc, off);
    }
    if (lane == 0) {
      sWP[0 + wave] = pa; sWP[16 + wave] = pb; sWP[32 + wave] = pc;
    } else if (lane == 1) {
      sWP[8 + wave] = pa; sWP[24 + wave] = pb;
    }
    __syncthreads();  // C

    // ---- finalize on ALL threads (bit-identical), state stays in registers ----
    float ov = (lane < 40) ? sWP[lane] : 0.0f;  // lane = m*8 + w
    ov += __shfl_xor(ov, 1);
    ov += __shfl_xor(ov, 2);
    ov += __shfl_xor(ov, 4);
    float o0 = __shfl(ov, 0) + bo0;
    float o1 = __shfl(ov, 8) + bo1;
    float o2 = __shfl(ov, 16) + bo2;
    float o3 = __shfl(ov, 24) + bo3;
    float o4 = __shfl(ov, 32) + bo4;
    if (tid == 0) {
      gout[t] = o4;           // q_output[t] = raw mlp output m=4 at state_t
      gout[TT + t] = s0;      // s_snow_nn[t] (pre-update)
      gout[2 * TT + t] = s1;  // s_water_nn[t]
    }
    float sh0 = xsinh(o0), sh1 = xsinh(o1), sh2 = xsinh(o2);
    float e3 = xexp(o3), e4 = xexp(o4);
    float stn = xstep(-tm), st0 = xstep(s0), st1 = xstep(s1);
    float psn = fmaxf(sh0 * stn, 0.0f);
    float prn = fmaxf(sh1, 0.0f);
    float mm = fmaxf(st0 * sh2, 0.0f);
    float evt = st1 * e3 * ld;
    float qq = st1 * e4;
    s0 += psn - mm;                 // DT = 1
    s1 += prn + mm - evt - qq;
  }
}

extern "C" void kernel_launch(void* const* d_in, const int* in_sizes, int n_in,
                              void* d_out, int out_size, void* d_ws, size_t ws_size,
                              hipStream_t stream) {
  const float* gin   = (const float*)d_in[0];
  const float* gdayl = (const float*)d_in[1];
  const float* gW0   = (const float*)d_in[2];
  const float* gb0   = (const float*)d_in[3];
  const float* gW1   = (const float*)d_in[4];
  const float* gb1   = (const float*)d_in[5];
  const float* gW2   = (const float*)d_in[6];
  const float* gb2   = (const float*)d_in[7];
  const float* gWout = (const float*)d_in[8];
  const float* gbout = (const float*)d_in[9];
  float* gout = (float*)d_out;
  exphydro_scan<<<dim3(1), dim3(512), 0, stream>>>(
      gin, gdayl, gW0, gb0, gW1, gb1, gW2, gb2, gWout, gbout, gout);
}

// Round 4
// 6668.433 us; speedup vs baseline: 1.0706x; 1.0055x over previous
//
#include <hip/hip_runtime.h>
#include <hip/hip_bf16.h>

#define TT 3650
#define HH 256

typedef _Float16 f16x2 __attribute__((ext_vector_type(2)));
typedef _Float16 f16x8 __attribute__((ext_vector_type(8)));
struct H4q { f16x2 a, b, c, d; };

__device__ __forceinline__ float xexp2(float x) { return __builtin_amdgcn_exp2f(x); }
__device__ __forceinline__ float xrcp(float x) { return __builtin_amdgcn_rcpf(x); }
__device__ __forceinline__ float xexp(float x) { return xexp2(x * 1.4426950408889634f); }
__device__ __forceinline__ float xtanh(float x) {
  float e = xexp2(x * 2.8853900817779268f);  // e^{2x}
  return 1.0f - 2.0f * xrcp(e + 1.0f);
}
// _step_function(x) = (tanh(5x)+1)/2 == sigmoid(10x)
__device__ __forceinline__ float xstep(float x) {
  return xrcp(1.0f + xexp2(-14.426950408889634f * x));
}
__device__ __forceinline__ float xsinh(float x) {
  float e = xexp(x);
  return 0.5f * (e - xrcp(e));
}

#if __has_builtin(__builtin_amdgcn_fdot2)
__device__ __forceinline__ float xdot2(f16x2 a, f16x2 b, float c) {
  return __builtin_amdgcn_fdot2(a, b, c, false);
}
#else
__device__ __forceinline__ float xdot2(f16x2 a, f16x2 b, float c) {
  return c + (float)a[0] * (float)b[0] + (float)a[1] * (float)b[1];
}
#endif

#define REP64(M) M(0) M(1) M(2) M(3) M(4) M(5) M(6) M(7) M(8) M(9) M(10) M(11) \
  M(12) M(13) M(14) M(15) M(16) M(17) M(18) M(19) M(20) M(21) M(22) M(23) \
  M(24) M(25) M(26) M(27) M(28) M(29) M(30) M(31) M(32) M(33) M(34) M(35) \
  M(36) M(37) M(38) M(39) M(40) M(41) M(42) M(43) M(44) M(45) M(46) M(47) \
  M(48) M(49) M(50) M(51) M(52) M(53) M(54) M(55) M(56) M(57) M(58) M(59) \
  M(60) M(61) M(62) M(63)

__global__ void __launch_bounds__(512)
    __attribute__((amdgpu_waves_per_eu(2, 2))) exphydro_scan(
    const float* __restrict__ gin, const float* __restrict__ gdayl,
    const float* __restrict__ gW0, const float* __restrict__ gb0,
    const float* __restrict__ gW1, const float* __restrict__ gb1,
    const float* __restrict__ gW2, const float* __restrict__ gb2,
    const float* __restrict__ gWout, const float* __restrict__ gbout,
    float* __restrict__ gout) {
  // activations: halves separated by 16B pad so the two per-wave broadcast
  // addresses of each ds_read_b128 land on disjoint bank groups
  __shared__ alignas(16) _Float16 h0h[HH + 8];
  __shared__ alignas(16) _Float16 h1h[HH + 8];
  __shared__ float sWP[64];                  // [m][wave] partials, m*8+w, 40 used
  __shared__ float sP[TT], sTm[TT], sLd[TT]; // staged forcings (43.8 KB)

  const int tid = threadIdx.x;
  const int j = tid >> 1;      // output neuron 0..255
  const int q = tid & 1;       // k-half 0..1 (k in [128q, 128q+128))
  const int lane = tid & 63;

  // ---- stage forcings to LDS ----
  for (int i = tid; i < TT; i += 512) {
    sP[i] = gin[5 * i + 2];
    sTm[i] = gin[5 * i + 3];
    sLd[i] = gdayl[i];
  }

  // ---- per-thread constants in registers (uniform ones become s_loads) ----
  float s0 = gin[0], s1 = gin[1];
  const float bo0 = gbout[0], bo1 = gbout[1], bo2 = gbout[2], bo3 = gbout[3],
              bo4 = gbout[4];
  const float w00 = gW0[j], w01 = gW0[HH + j], w02 = gW0[2 * HH + j],
              w03 = gW0[3 * HH + j];
  const float b0 = gb0[j], b1 = gb1[j], b2 = gb2[j];
  const float wo_a = gWout[5 * j + q];       // m = q
  const float wo_b = gWout[5 * j + 2 + q];   // m = 2+q
  const float wo_c = gWout[5 * j + 4];       // m = 4 (used by q==0)

  // ---- one-time: big weights into 128 NAMED registers as packed fp16 ----
  // thread (j,q) holds W1[k][j], W2[k][j] for k in [128q,128q+128):
  // w1_i = {W1[kbase+2i][j], W1[kbase+2i+1][j]}  (no arrays -> no alloca -> no scratch)
  const int kbase = q * 128;
#define WDECL(i) f16x2 w1_##i, w2_##i;
  REP64(WDECL)
#undef WDECL
#define WINIT(i)                                                            \
  {                                                                         \
    const float* p1 = gW1 + (kbase + 2 * (i)) * HH + j;                     \
    const float* p2 = gW2 + (kbase + 2 * (i)) * HH + j;                     \
    w1_##i = f16x2{(_Float16)p1[0], (_Float16)p1[HH]};                      \
    w2_##i = f16x2{(_Float16)p2[0], (_Float16)p2[HH]};                      \
  }
  REP64(WINIT)
#undef WINIT

  const char* hb0 = (const char*)h0h + q * 272;  // this thread's 128-half window
  const char* hb1 = (const char*)h1h + q * 272;
  const int jw = j + ((j & 128) >> 4);           // +8 elements for upper half

  __syncthreads();  // staging visible

  for (int t = 0; t < TT; ++t) {
    const float p_in = sP[t];
    const float tm = sTm[t];
    const float ld = sLd[t];

    // ---- layer 0 (2x redundant across q) ----
    float z0 = b0 + s0 * w00 + s1 * w01 + p_in * w02 + tm * w03;
    float h0v = xtanh(z0);
    if (q == 0) h0h[jw] = (_Float16)h0v;
    __syncthreads();  // A

    // ---- layer 1: 64 fdot2 over this thread's k-half ----
    float a0 = 0.f, a1 = 0.f, a2 = 0.f, a3 = 0.f;
#define LSTEP(s, hb, wA, wB, wC, wD)                                        \
  {                                                                         \
    f16x8 hv = *(const f16x8*)((hb) + (s) * 16);                            \
    H4q hp = __builtin_bit_cast(H4q, hv);                                   \
    a0 = xdot2(hp.a, wA, a0);                                               \
    a1 = xdot2(hp.b, wB, a1);                                               \
    a2 = xdot2(hp.c, wC, a2);                                               \
    a3 = xdot2(hp.d, wD, a3);                                               \
  }
    LSTEP(0, hb0, w1_0, w1_1, w1_2, w1_3)
    LSTEP(1, hb0, w1_4, w1_5, w1_6, w1_7)
    LSTEP(2, hb0, w1_8, w1_9, w1_10, w1_11)
    LSTEP(3, hb0, w1_12, w1_13, w1_14, w1_15)
    LSTEP(4, hb0, w1_16, w1_17, w1_18, w1_19)
    LSTEP(5, hb0, w1_20, w1_21, w1_22, w1_23)
    LSTEP(6, hb0, w1_24, w1_25, w1_26, w1_27)
    LSTEP(7, hb0, w1_28, w1_29, w1_30, w1_31)
    LSTEP(8, hb0, w1_32, w1_33, w1_34, w1_35)
    LSTEP(9, hb0, w1_36, w1_37, w1_38, w1_39)
    LSTEP(10, hb0, w1_40, w1_41, w1_42, w1_43)
    LSTEP(11, hb0, w1_44, w1_45, w1_46, w1_47)
    LSTEP(12, hb0, w1_48, w1_49, w1_50, w1_51)
    LSTEP(13, hb0, w1_52, w1_53, w1_54, w1_55)
    LSTEP(14, hb0, w1_56, w1_57, w1_58, w1_59)
    LSTEP(15, hb0, w1_60, w1_61, w1_62, w1_63)
    float z1 = (a0 + a1) + (a2 + a3);
    z1 += __shfl_xor(z1, 1);  // combine the two k-halves
    float h1v = xtanh(z1 + b1);
    if (q == 0) h1h[jw] = (_Float16)h1v;
    __syncthreads();  // B

    // ---- layer 2 ----
    a0 = 0.f; a1 = 0.f; a2 = 0.f; a3 = 0.f;
    LSTEP(0, hb1, w2_0, w2_1, w2_2, w2_3)
    LSTEP(1, hb1, w2_4, w2_5, w2_6, w2_7)
    LSTEP(2, hb1, w2_8, w2_9, w2_10, w2_11)
    LSTEP(3, hb1, w2_12, w2_13, w2_14, w2_15)
    LSTEP(4, hb1, w2_16, w2_17, w2_18, w2_19)
    LSTEP(5, hb1, w2_20, w2_21, w2_22, w2_23)
    LSTEP(6, hb1, w2_24, w2_25, w2_26, w2_27)
    LSTEP(7, hb1, w2_28, w2_29, w2_30, w2_31)
    LSTEP(8, hb1, w2_32, w2_33, w2_34, w2_35)
    LSTEP(9, hb1, w2_36, w2_37, w2_38, w2_39)
    LSTEP(10, hb1, w2_40, w2_41, w2_42, w2_43)
    LSTEP(11, hb1, w2_44, w2_45, w2_46, w2_47)
    LSTEP(12, hb1, w2_48, w2_49, w2_50, w2_51)
    LSTEP(13, hb1, w2_52, w2_53, w2_54, w2_55)
    LSTEP(14, hb1, w2_56, w2_57, w2_58, w2_59)
    LSTEP(15, hb1, w2_60, w2_61, w2_62, w2_63)
#undef LSTEP
    float z2 = (a0 + a1) + (a2 + a3);
    z2 += __shfl_xor(z2, 1);
    float h2v = xtanh(z2 + b2);

    // ---- output partials: in-wave reduce over j (q-parity carries m pairs) ----
    float pa = h2v * wo_a;                    // m = q
    float pb = h2v * wo_b;                    // m = 2+q
    float pc = (q == 0) ? h2v * wo_c : 0.0f;  // m = 4
#pragma unroll
    for (int off = 2; off < 64; off <<= 1) {
      pa += __shfl_xor(pa, off);
      pb += __shfl_xor(pb, off);
      pc += __shfl_xor(pc, off);
    }
    {
      const int wave = tid >> 6;
      if (lane == 0) {
        sWP[0 + wave] = pa; sWP[16 + wave] = pb; sWP[32 + wave] = pc;
      } else if (lane == 1) {
        sWP[8 + wave] = pa; sWP[24 + wave] = pb;
      }
    }
    __syncthreads();  // C

    // ---- finalize on ALL threads (bit-identical), state stays in registers ----
    float ov = (lane < 40) ? sWP[lane] : 0.0f;  // lane = m*8 + w
    ov += __shfl_xor(ov, 1);
    ov += __shfl_xor(ov, 2);
    ov += __shfl_xor(ov, 4);
    float o0 = __shfl(ov, 0) + bo0;
    float o1 = __shfl(ov, 8) + bo1;
    float o2 = __shfl(ov, 16) + bo2;
    float o3 = __shfl(ov, 24) + bo3;
    float o4 = __shfl(ov, 32) + bo4;
    if (tid == 0) {
      gout[t] = o4;           // q_output[t] = raw mlp output m=4 at state_t
      gout[TT + t] = s0;      // s_snow_nn[t] (pre-update)
      gout[2 * TT + t] = s1;  // s_water_nn[t]
    }
    float sh0 = xsinh(o0), sh1 = xsinh(o1), sh2 = xsinh(o2);
    float e3 = xexp(o3), e4 = xexp(o4);
    float stn = xstep(-tm), st0 = xstep(s0), st1 = xstep(s1);
    float psn = fmaxf(sh0 * stn, 0.0f);
    float prn = fmaxf(sh1, 0.0f);
    float mm = fmaxf(st0 * sh2, 0.0f);
    float evt = st1 * e3 * ld;
    float qq = st1 * e4;
    s0 += psn - mm;                 // DT = 1
    s1 += prn + mm - evt - qq;
  }
}

extern "C" void kernel_launch(void* const* d_in, const int* in_sizes, int n_in,
                              void* d_out, int out_size, void* d_ws, size_t ws_size,
                              hipStream_t stream) {
  const float* gin   = (const float*)d_in[0];
  const float* gdayl = (const float*)d_in[1];
  const float* gW0   = (const float*)d_in[2];
  const float* gb0   = (const float*)d_in[3];
  const float* gW1   = (const float*)d_in[4];
  const float* gb1   = (const float*)d_in[5];
  const float* gW2   = (const float*)d_in[6];
  const float* gb2   = (const float*)d_in[7];
  const float* gWout = (const float*)d_in[8];
  const float* gbout = (const float*)d_in[9];
  float* gout = (float*)d_out;
  exphydro_scan<<<dim3(1), dim3(512), 0, stream>>>(
      gin, gdayl, gW0, gb0, gW1, gb1, gW2, gb2, gWout, gbout, gout);
}